// Round 5
// baseline (189.173 us; speedup 1.0000x reference)
//
#include <hip/hip_runtime.h>
#include <hip/hip_bf16.h>
#include <math.h>

#define TKN 16384
#define HID 4096
#define NE  256
#define TOPK 8
#define NGRP 8
#define TOPG 4

#define BM 128
#define BK 64
#define NKT (HID / BK)          // 64 K-steps
#define BIMG 32768              // prep'd B image per (cb,kt): [hi 16K][lo 16K]

typedef _Float16 half8 __attribute__((ext_vector_type(8)));
typedef float    f32x4 __attribute__((ext_vector_type(4)));

static __device__ __forceinline__ unsigned pkrtz(float x, float y) {
    auto r = __builtin_amdgcn_cvt_pkrtz(x, y);   // v_cvt_pkrtz_f16_f32
    return __builtin_bit_cast(unsigned, r);
}
static __device__ __forceinline__ float hi_mask(float a) {
    return __uint_as_float(__float_as_uint(a) & 0xFFFFE000u);
}

// ---- prep: B [256][4096] f32 -> pre-swizzled f16 hi/lo images in ws --------
// (verbatim from rounds 3/4 — validated; values feed MFMA bit-identically)
__global__ __launch_bounds__(256) void prep_b(const float* __restrict__ B,
                                              unsigned char* __restrict__ ws)
{
    const int gid = blockIdx.x * 256 + threadIdx.x;   // 131072
    const int e   = gid >> 9;          // expert 0..255
    const int k0  = (gid & 511) * 8;   // k chunk of 8
    const float* src = B + (size_t)e * HID + k0;
    float v[8];
    #pragma unroll
    for (int i = 0; i < 8; ++i) v[i] = src[i];
    unsigned hw[4], lw[4];
    #pragma unroll
    for (int j = 0; j < 4; ++j) {
        const float x0 = v[2*j], x1 = v[2*j+1];
        const float h0 = hi_mask(x0), h1 = hi_mask(x1);
        hw[j] = pkrtz(h0, h1);
        lw[j] = pkrtz(x0 - h0, x1 - h1);
    }
    const int cb  = e >> 7;
    const int row = e & 127;
    const int kt  = k0 >> 6;
    const int x   = ((k0 & 63) * 2) ^ ((row & 7) << 4);
    unsigned char* img = ws + (size_t)(cb * NKT + kt) * BIMG + row * 128 + x;
    *(uint4*)(img)         = make_uint4(hw[0], hw[1], hw[2], hw[3]);
    *(uint4*)(img + 16384) = make_uint4(lw[0], lw[1], lw[2], lw[3]);
}

// ---- GEMM: logits = A[T,H] @ B[E,H]^T, f16x2 split, 3 MFMA passes ----------
// Arithmetic sequence is bit-identical to the round-3 passing kernel:
// 16 waves = wg(2, split-K halves) x wr(2) x wc(4); per kt each wave does its
// 64-byte K-half; per (mt,nt): mfma(ah,bh), mfma(ah,bl), mfma(al,bh);
// epilogue: o = acc(wg0) + acc(wg1). Only data MOVEMENT changed:
// B frags come straight from the prep'd L2-resident image (no LDS),
// A uses dense-XOR LDS (round-2-proven addressing).
__global__ __launch_bounds__(1024, 4) void gemm_mfma(
    const float* __restrict__ A, const unsigned char* __restrict__ Bws,
    float* __restrict__ C)
{
    __shared__ __align__(16) unsigned char smem[2][2][16384];   // 64 KiB: [buf][hi/lo][128x128B]

    const int tid  = threadIdx.x;
    const int lane = tid & 63;
    const int wave = tid >> 6;
    const int wg = wave >> 3;           // split-K half
    const int wr = (wave >> 2) & 1;     // row 64-half
    const int wc = wave & 3;            // col 32-quarter

    // XCD-aware remap: cb-twins (same A panel) on same XCD; contiguous A slab per XCD
    const int bid  = blockIdx.x;
    const int mb   = (bid & 7) * 16 + (bid >> 4);
    const int cb   = (bid >> 3) & 1;
    const int row0 = mb * BM;

    // A staging: thread owns 8 consecutive k-floats of one row
    const int arow = tid >> 3;                   // 0..127
    const int aseg = (tid & 7) * 8;              // float idx 0..56
    const float* aG = A + (size_t)(row0 + arow) * HID + aseg;
    const int awx = arow * 128 + ((aseg * 2) ^ ((arow & 7) << 4));

    // fragment addressing (XOR term lane-constant; same involution as store)
    const int kx    = ((wg * 64) + ((lane >> 4) << 4)) ^ ((lane & 7) << 4);
    const int aRowB = (wr * 64 + (lane & 15)) * 128;
    const unsigned char* bBase = Bws + (size_t)cb * NKT * BIMG;
    const int boff0 = (wc * 32 + (lane & 15)) * 128 + kx;
    const int boff1 = boff0 + 16 * 128;

    f32x4 acc[4][2];
    #pragma unroll
    for (int i = 0; i < 4; ++i) { acc[i][0] = (f32x4)0.f; acc[i][1] = (f32x4)0.f; }

    float4 v0, v1;

    // prologue: stage A tile 0 into buf 0
    v0 = *(const float4*)(aG);
    v1 = *(const float4*)(aG + 4);
    {
        const float h0 = hi_mask(v0.x), h1 = hi_mask(v0.y),
                    h2 = hi_mask(v0.z), h3 = hi_mask(v0.w);
        const float h4 = hi_mask(v1.x), h5 = hi_mask(v1.y),
                    h6 = hi_mask(v1.z), h7 = hi_mask(v1.w);
        *(uint4*)&smem[0][0][awx] = make_uint4(pkrtz(h0, h1), pkrtz(h2, h3),
                                               pkrtz(h4, h5), pkrtz(h6, h7));
        *(uint4*)&smem[0][1][awx] = make_uint4(pkrtz(v0.x - h0, v0.y - h1),
                                               pkrtz(v0.z - h2, v0.w - h3),
                                               pkrtz(v1.x - h4, v1.y - h5),
                                               pkrtz(v1.z - h6, v1.w - h7));
    }
    __syncthreads();

    for (int kt = 0; kt < NKT; ++kt) {
        const unsigned char* ub = &smem[kt & 1][0][0];
        const bool more = (kt != NKT - 1);

        // next A tile (HBM, longest latency) first
        if (more) {
            v0 = *(const float4*)(aG + (kt + 1) * BK);
            v1 = *(const float4*)(aG + (kt + 1) * BK + 4);
        }
        // this kt's B fragments straight from L2-resident image
        const unsigned char* bp = bBase + (size_t)kt * BIMG;
        const half8 bh0 = *(const half8*)(bp + boff0);
        const half8 bl0 = *(const half8*)(bp + 16384 + boff0);
        const half8 bh1 = *(const half8*)(bp + boff1);
        const half8 bl1 = *(const half8*)(bp + 16384 + boff1);
        __builtin_amdgcn_sched_barrier(0);

        #pragma unroll
        for (int mt = 0; mt < 4; ++mt) {
            const half8 ah = *(const half8*)(ub + aRowB + mt * 2048 + kx);
            const half8 al = *(const half8*)(ub + 16384 + aRowB + mt * 2048 + kx);
            f32x4 c0 = acc[mt][0];
            c0 = __builtin_amdgcn_mfma_f32_16x16x32_f16(ah, bh0, c0, 0, 0, 0);
            c0 = __builtin_amdgcn_mfma_f32_16x16x32_f16(ah, bl0, c0, 0, 0, 0);
            c0 = __builtin_amdgcn_mfma_f32_16x16x32_f16(al, bh0, c0, 0, 0, 0);
            acc[mt][0] = c0;
            f32x4 c1 = acc[mt][1];
            c1 = __builtin_amdgcn_mfma_f32_16x16x32_f16(ah, bh1, c1, 0, 0, 0);
            c1 = __builtin_amdgcn_mfma_f32_16x16x32_f16(ah, bl1, c1, 0, 0, 0);
            c1 = __builtin_amdgcn_mfma_f32_16x16x32_f16(al, bh1, c1, 0, 0, 0);
            acc[mt][1] = c1;
        }

        // stage next A tile into other buffer (loads had full MFMA section)
        if (more) {
            const int nb = (kt + 1) & 1;
            const float h0 = hi_mask(v0.x), h1 = hi_mask(v0.y),
                        h2 = hi_mask(v0.z), h3 = hi_mask(v0.w);
            const float h4 = hi_mask(v1.x), h5 = hi_mask(v1.y),
                        h6 = hi_mask(v1.z), h7 = hi_mask(v1.w);
            *(uint4*)&smem[nb][0][awx] = make_uint4(pkrtz(h0, h1), pkrtz(h2, h3),
                                                    pkrtz(h4, h5), pkrtz(h6, h7));
            *(uint4*)&smem[nb][1][awx] = make_uint4(pkrtz(v0.x - h0, v0.y - h1),
                                                    pkrtz(v0.z - h2, v0.w - h3),
                                                    pkrtz(v1.x - h4, v1.y - h5),
                                                    pkrtz(v1.z - h6, v1.w - h7));
        }
        __syncthreads();
    }

    // epilogue: reduce wg1 into wg0 through LDS (round-3 verbatim), write C
    float* redf = (float*)&smem[0][0][0];            // 64 KB scratch
    const int fb = (wave & 7) * 2048 + lane * 4;     // float index
    if (wg == 1) {
        #pragma unroll
        for (int mt = 0; mt < 4; ++mt)
            #pragma unroll
            for (int nt = 0; nt < 2; ++nt)
                *(f32x4*)&redf[fb + (mt * 2 + nt) * 256] = acc[mt][nt];
    }
    __syncthreads();
    if (wg == 0) {
        #pragma unroll
        for (int mt = 0; mt < 4; ++mt) {
            #pragma unroll
            for (int nt = 0; nt < 2; ++nt) {
                f32x4 o = acc[mt][nt] + *(const f32x4*)&redf[fb + (mt * 2 + nt) * 256];
                const int r0 = row0 + wr * 64 + mt * 16 + (lane >> 4) * 4;
                const int cc = cb * 128 + wc * 32 + nt * 16 + (lane & 15);
                #pragma unroll
                for (int r = 0; r < 4; ++r)
                    C[(size_t)(r0 + r) * NE + cc] = o[r];
            }
        }
    }
}

// ---------------- Router: per-token top-k (verified rounds 1-3) -------------
__global__ __launch_bounds__(256) void router_topk_kernel(
    const float* __restrict__ logits, const float* __restrict__ bias,
    float* __restrict__ out_w, float* __restrict__ out_i)
{
    const int wid  = threadIdx.x >> 6;
    const int lane = threadIdx.x & 63;
    const int token = blockIdx.x * 4 + wid;

    const float* row = logits + (size_t)token * NE;
    const float4 lg = *(const float4*)&row[lane * 4];

    float sig[4], sc[4];
    {
        const float l4[4] = {lg.x, lg.y, lg.z, lg.w};
        #pragma unroll
        for (int j = 0; j < 4; ++j) {
            sig[j] = 1.f / (1.f + expf(-l4[j]));
            sc[j]  = sig[j] + bias[lane * 4 + j];
        }
    }

    float m1 = sc[0], m2 = -INFINITY;
    #pragma unroll
    for (int j = 1; j < 4; ++j) {
        if (sc[j] > m1) { m2 = m1; m1 = sc[j]; }
        else if (sc[j] > m2) { m2 = sc[j]; }
    }
    #pragma unroll
    for (int off = 1; off < 8; off <<= 1) {
        const float o1 = __shfl_xor(m1, off);
        const float o2 = __shfl_xor(m2, off);
        const float lo = fminf(m1, o1);
        m1 = fmaxf(m1, o1);
        m2 = fmaxf(lo, fmaxf(m2, o2));
    }
    const float gscore = m1 + m2;

    const int gmy = lane >> 3;
    int rank = 0;
    #pragma unroll
    for (int g = 0; g < NGRP; ++g) {
        const float gs = __shfl(gscore, g * 8);
        if (gs > gscore || (gs == gscore && g < gmy)) ++rank;
    }
    if (rank >= TOPG) {
        #pragma unroll
        for (int j = 0; j < 4; ++j) sc[j] = -INFINITY;
    }

    float wk[TOPK]; int ik[TOPK];
    float wsum = 0.f;
    #pragma unroll
    for (int k = 0; k < TOPK; ++k) {
        float bv = sc[0]; int bi = lane * 4;
        #pragma unroll
        for (int j = 1; j < 4; ++j)
            if (sc[j] > bv) { bv = sc[j]; bi = lane * 4 + j; }
        #pragma unroll
        for (int off = 1; off < 64; off <<= 1) {
            const float v2 = __shfl_xor(bv, off);
            const int   i2 = __shfl_xor(bi, off);
            if (v2 > bv || (v2 == bv && i2 < bi)) { bv = v2; bi = i2; }
        }
        const int owner = bi >> 2;
        const int j = bi & 3;
        const float sv = (j == 0) ? sig[0] : (j == 1) ? sig[1] : (j == 2) ? sig[2] : sig[3];
        const float w = __shfl(sv, owner);
        wk[k] = w; ik[k] = bi; wsum += w;
        if (lane == owner) {
            if (j == 0) sc[0] = -INFINITY;
            else if (j == 1) sc[1] = -INFINITY;
            else if (j == 2) sc[2] = -INFINITY;
            else sc[3] = -INFINITY;
        }
    }

    if (lane == 0) {
        const float denom = wsum + 1e-20f;
        #pragma unroll
        for (int k = 0; k < TOPK; ++k) {
            out_w[(size_t)token * TOPK + k] = wk[k] / denom;
            out_i[(size_t)token * TOPK + k] = (float)ik[k];
        }
    }
}

extern "C" void kernel_launch(void* const* d_in, const int* in_sizes, int n_in,
                              void* d_out, int out_size, void* d_ws, size_t ws_size,
                              hipStream_t stream) {
    const float* hidden = (const float*)d_in[0];
    const float* weight = (const float*)d_in[1];
    const float* bias   = (const float*)d_in[2];

    float* logits = (float*)d_out;                              // [T, E]
    float* out_w  = logits + (size_t)TKN * NE;                  // [T, 8]
    float* out_i  = out_w + (size_t)TKN * TOPK;                 // [T, 8]

    unsigned char* bpl = (unsigned char*)d_ws;                  // 4 MB B planes

    prep_b<<<512, 256, 0, stream>>>(weight, bpl);
    gemm_mfma<<<256, 1024, 0, stream>>>(hidden, bpl, logits);
    router_topk_kernel<<<TKN / 4, 256, 0, stream>>>(logits, bias, out_w, out_i);
}

// Round 6
// 164.996 us; speedup vs baseline: 1.1465x; 1.1465x over previous
//
#include <hip/hip_runtime.h>
#include <hip/hip_bf16.h>
#include <math.h>

#define TKN 16384
#define HID 4096
#define NE  256
#define TOPK 8
#define NGRP 8
#define TOPG 4

#define BM 128
#define BK 64
#define NKT (HID / BK)          // 64 K-steps
#define BIMG 32768              // prep'd B image per (cb,kt): [hi 16K][lo 16K]

typedef _Float16 half8 __attribute__((ext_vector_type(8)));
typedef float    f32x4 __attribute__((ext_vector_type(4)));

static __device__ __forceinline__ unsigned pkrtz(float x, float y) {
    auto r = __builtin_amdgcn_cvt_pkrtz(x, y);   // v_cvt_pkrtz_f16_f32
    return __builtin_bit_cast(unsigned, r);
}
static __device__ __forceinline__ float hi_mask(float a) {
    return __uint_as_float(__float_as_uint(a) & 0xFFFFE000u);
}

// ---- prep: B [256][4096] f32 -> FRAGMENT-ORDERED f16 hi/lo images ----------
// Layout within (cb,kt) image: plane*16K + (((rowgrp*2+wg)*4+kseg)*16+lane16)*16
// so a wave's fragment load is base + lane*16 (1KB contiguous).
// Values are the identical f16 hi/lo pairs of rounds 3/5 (bit-identical MFMA inputs).
__global__ __launch_bounds__(256) void prep_b(const float* __restrict__ B,
                                              unsigned char* __restrict__ ws)
{
    const int gid = blockIdx.x * 256 + threadIdx.x;   // 131072
    const int e   = gid >> 9;          // expert 0..255
    const int k0  = (gid & 511) * 8;   // k chunk of 8
    const float* src = B + (size_t)e * HID + k0;
    float v[8];
    #pragma unroll
    for (int i = 0; i < 8; ++i) v[i] = src[i];
    unsigned hw[4], lw[4];
    #pragma unroll
    for (int j = 0; j < 4; ++j) {
        const float x0 = v[2*j], x1 = v[2*j+1];
        const float h0 = hi_mask(x0), h1 = hi_mask(x1);
        hw[j] = pkrtz(h0, h1);
        lw[j] = pkrtz(x0 - h0, x1 - h1);
    }
    const int cb     = e >> 7;
    const int row    = e & 127;
    const int rowgrp = row >> 4;
    const int lane16 = row & 15;
    const int kt     = k0 >> 6;
    const int kk     = k0 & 63;
    const int wg     = kk >> 5;
    const int kseg   = (kk >> 3) & 3;
    const int idx16  = ((rowgrp * 2 + wg) * 4 + kseg) * 16 + lane16;
    unsigned char* img = ws + (size_t)(cb * NKT + kt) * BIMG + idx16 * 16;
    *(uint4*)(img)         = make_uint4(hw[0], hw[1], hw[2], hw[3]);
    *(uint4*)(img + 16384) = make_uint4(lw[0], lw[1], lw[2], lw[3]);
}

// ---- GEMM: logits = A[T,H] @ B[E,H]^T, f16x2 split, 3 MFMA passes ----------
// Arithmetic (per-accumulator MFMA sequence + split-K epilogue add) is
// bit-identical to the round-3/5 passing kernels. Changes are movement-only:
// coalesced fragment-ordered B image + 1-step register prefetch of B.
__global__ __launch_bounds__(1024, 4) void gemm_mfma(
    const float* __restrict__ A, const unsigned char* __restrict__ Bws,
    float* __restrict__ C)
{
    __shared__ __align__(16) unsigned char smem[2][2][16384];   // 64 KiB

    const int tid  = threadIdx.x;
    const int lane = tid & 63;
    const int wave = tid >> 6;
    const int wg = wave >> 3;           // split-K half
    const int wr = (wave >> 2) & 1;     // row 64-half
    const int wc = wave & 3;            // col 32-quarter

    const int bid  = blockIdx.x;
    const int mb   = (bid & 7) * 16 + (bid >> 4);
    const int cb   = (bid >> 3) & 1;
    const int row0 = mb * BM;

    // A staging: thread owns 8 consecutive k-floats of one row
    const int arow = tid >> 3;                   // 0..127
    const int aseg = (tid & 7) * 8;              // float idx 0..56
    const float* aG = A + (size_t)(row0 + arow) * HID + aseg;
    const int awx = arow * 128 + ((aseg * 2) ^ ((arow & 7) << 4));

    // A fragment addressing (lane-constant XOR, round-2-verified)
    const int kx    = ((wg * 64) + ((lane >> 4) << 4)) ^ ((lane & 7) << 4);
    const int aRowB = (wr * 64 + (lane & 15)) * 128;

    // B fragment addressing: contiguous 1KB per wave-fragment
    const unsigned char* bBase = Bws + (size_t)cb * NKT * BIMG;
    const int boffH0 = ((wc * 2 + 0) * 2 + wg) * 1024 + lane * 16;
    const int boffH1 = ((wc * 2 + 1) * 2 + wg) * 1024 + lane * 16;

    f32x4 acc[4][2];
    #pragma unroll
    for (int i = 0; i < 4; ++i) { acc[i][0] = (f32x4)0.f; acc[i][1] = (f32x4)0.f; }

    float4 v0, v1;
    half8 bC[4], bN[4];   // [h0, l0, h1, l1] current / next

    // prologue: A tile 0 -> buf 0; B frags kt=0 -> bC
    v0 = *(const float4*)(aG);
    v1 = *(const float4*)(aG + 4);
    bC[0] = *(const half8*)(bBase + boffH0);
    bC[1] = *(const half8*)(bBase + 16384 + boffH0);
    bC[2] = *(const half8*)(bBase + boffH1);
    bC[3] = *(const half8*)(bBase + 16384 + boffH1);
    {
        const float h0 = hi_mask(v0.x), h1 = hi_mask(v0.y),
                    h2 = hi_mask(v0.z), h3 = hi_mask(v0.w);
        const float h4 = hi_mask(v1.x), h5 = hi_mask(v1.y),
                    h6 = hi_mask(v1.z), h7 = hi_mask(v1.w);
        *(uint4*)&smem[0][0][awx] = make_uint4(pkrtz(h0, h1), pkrtz(h2, h3),
                                               pkrtz(h4, h5), pkrtz(h6, h7));
        *(uint4*)&smem[0][1][awx] = make_uint4(pkrtz(v0.x - h0, v0.y - h1),
                                               pkrtz(v0.z - h2, v0.w - h3),
                                               pkrtz(v1.x - h4, v1.y - h5),
                                               pkrtz(v1.z - h6, v1.w - h7));
    }
    __syncthreads();

#define GSTEP(KT, BCUR, BNXT)                                                  \
    {                                                                          \
        const int kt_ = (KT);                                                  \
        const unsigned char* ub = &smem[kt_ & 1][0][0];                        \
        const bool more = (kt_ != NKT - 1);                                    \
        if (more) {  /* issue kt+1 loads: A (HBM) and B (L2) */                \
            v0 = *(const float4*)(aG + (kt_ + 1) * BK);                        \
            v1 = *(const float4*)(aG + (kt_ + 1) * BK + 4);                    \
            const unsigned char* bp = bBase + (size_t)(kt_ + 1) * BIMG;        \
            BNXT[0] = *(const half8*)(bp + boffH0);                            \
            BNXT[1] = *(const half8*)(bp + 16384 + boffH0);                    \
            BNXT[2] = *(const half8*)(bp + boffH1);                            \
            BNXT[3] = *(const half8*)(bp + 16384 + boffH1);                    \
        }                                                                      \
        __builtin_amdgcn_sched_barrier(0);                                     \
        _Pragma("unroll")                                                      \
        for (int mt = 0; mt < 4; ++mt) {                                       \
            const half8 ah = *(const half8*)(ub + aRowB + mt * 2048 + kx);     \
            const half8 al = *(const half8*)(ub + 16384 + aRowB + mt * 2048 + kx); \
            f32x4 c0 = acc[mt][0];                                             \
            c0 = __builtin_amdgcn_mfma_f32_16x16x32_f16(ah, BCUR[0], c0, 0, 0, 0); \
            c0 = __builtin_amdgcn_mfma_f32_16x16x32_f16(ah, BCUR[1], c0, 0, 0, 0); \
            c0 = __builtin_amdgcn_mfma_f32_16x16x32_f16(al, BCUR[0], c0, 0, 0, 0); \
            acc[mt][0] = c0;                                                   \
            f32x4 c1 = acc[mt][1];                                             \
            c1 = __builtin_amdgcn_mfma_f32_16x16x32_f16(ah, BCUR[2], c1, 0, 0, 0); \
            c1 = __builtin_amdgcn_mfma_f32_16x16x32_f16(ah, BCUR[3], c1, 0, 0, 0); \
            c1 = __builtin_amdgcn_mfma_f32_16x16x32_f16(al, BCUR[2], c1, 0, 0, 0); \
            acc[mt][1] = c1;                                                   \
        }                                                                      \
        if (more) {  /* stage kt+1 A (loads had the full MFMA section) */      \
            const int nb = (kt_ + 1) & 1;                                      \
            const float h0 = hi_mask(v0.x), h1 = hi_mask(v0.y),                \
                        h2 = hi_mask(v0.z), h3 = hi_mask(v0.w);                \
            const float h4 = hi_mask(v1.x), h5 = hi_mask(v1.y),                \
                        h6 = hi_mask(v1.z), h7 = hi_mask(v1.w);                \
            *(uint4*)&smem[nb][0][awx] = make_uint4(pkrtz(h0, h1), pkrtz(h2, h3), \
                                                    pkrtz(h4, h5), pkrtz(h6, h7)); \
            *(uint4*)&smem[nb][1][awx] = make_uint4(pkrtz(v0.x - h0, v0.y - h1), \
                                                    pkrtz(v0.z - h2, v0.w - h3), \
                                                    pkrtz(v1.x - h4, v1.y - h5), \
                                                    pkrtz(v1.z - h6, v1.w - h7)); \
        }                                                                      \
        __syncthreads();                                                       \
    }

    for (int kt = 0; kt < NKT; kt += 2) {
        GSTEP(kt, bC, bN);
        GSTEP(kt + 1, bN, bC);
    }
#undef GSTEP

    // epilogue: reduce wg1 into wg0 through LDS (rounds-3/5 verbatim), write C
    float* redf = (float*)&smem[0][0][0];            // 64 KB scratch
    const int fb = (wave & 7) * 2048 + lane * 4;     // float index
    if (wg == 1) {
        #pragma unroll
        for (int mt = 0; mt < 4; ++mt)
            #pragma unroll
            for (int nt = 0; nt < 2; ++nt)
                *(f32x4*)&redf[fb + (mt * 2 + nt) * 256] = acc[mt][nt];
    }
    __syncthreads();
    if (wg == 0) {
        #pragma unroll
        for (int mt = 0; mt < 4; ++mt) {
            #pragma unroll
            for (int nt = 0; nt < 2; ++nt) {
                f32x4 o = acc[mt][nt] + *(const f32x4*)&redf[fb + (mt * 2 + nt) * 256];
                const int r0 = row0 + wr * 64 + mt * 16 + (lane >> 4) * 4;
                const int cc = cb * 128 + wc * 32 + nt * 16 + (lane & 15);
                #pragma unroll
                for (int r = 0; r < 4; ++r)
                    C[(size_t)(r0 + r) * NE + cc] = o[r];
            }
        }
    }
}

// ---------------- Router: per-token top-k (verified rounds 1-3, 5) ----------
__global__ __launch_bounds__(256) void router_topk_kernel(
    const float* __restrict__ logits, const float* __restrict__ bias,
    float* __restrict__ out_w, float* __restrict__ out_i)
{
    const int wid  = threadIdx.x >> 6;
    const int lane = threadIdx.x & 63;
    const int token = blockIdx.x * 4 + wid;

    const float* row = logits + (size_t)token * NE;
    const float4 lg = *(const float4*)&row[lane * 4];

    float sig[4], sc[4];
    {
        const float l4[4] = {lg.x, lg.y, lg.z, lg.w};
        #pragma unroll
        for (int j = 0; j < 4; ++j) {
            sig[j] = 1.f / (1.f + expf(-l4[j]));
            sc[j]  = sig[j] + bias[lane * 4 + j];
        }
    }

    float m1 = sc[0], m2 = -INFINITY;
    #pragma unroll
    for (int j = 1; j < 4; ++j) {
        if (sc[j] > m1) { m2 = m1; m1 = sc[j]; }
        else if (sc[j] > m2) { m2 = sc[j]; }
    }
    #pragma unroll
    for (int off = 1; off < 8; off <<= 1) {
        const float o1 = __shfl_xor(m1, off);
        const float o2 = __shfl_xor(m2, off);
        const float lo = fminf(m1, o1);
        m1 = fmaxf(m1, o1);
        m2 = fmaxf(lo, fmaxf(m2, o2));
    }
    const float gscore = m1 + m2;

    const int gmy = lane >> 3;
    int rank = 0;
    #pragma unroll
    for (int g = 0; g < NGRP; ++g) {
        const float gs = __shfl(gscore, g * 8);
        if (gs > gscore || (gs == gscore && g < gmy)) ++rank;
    }
    if (rank >= TOPG) {
        #pragma unroll
        for (int j = 0; j < 4; ++j) sc[j] = -INFINITY;
    }

    float wk[TOPK]; int ik[TOPK];
    float wsum = 0.f;
    #pragma unroll
    for (int k = 0; k < TOPK; ++k) {
        float bv = sc[0]; int bi = lane * 4;
        #pragma unroll
        for (int j = 1; j < 4; ++j)
            if (sc[j] > bv) { bv = sc[j]; bi = lane * 4 + j; }
        #pragma unroll
        for (int off = 1; off < 64; off <<= 1) {
            const float v2 = __shfl_xor(bv, off);
            const int   i2 = __shfl_xor(bi, off);
            if (v2 > bv || (v2 == bv && i2 < bi)) { bv = v2; bi = i2; }
        }
        const int owner = bi >> 2;
        const int j = bi & 3;
        const float sv = (j == 0) ? sig[0] : (j == 1) ? sig[1] : (j == 2) ? sig[2] : sig[3];
        const float w = __shfl(sv, owner);
        wk[k] = w; ik[k] = bi; wsum += w;
        if (lane == owner) {
            if (j == 0) sc[0] = -INFINITY;
            else if (j == 1) sc[1] = -INFINITY;
            else if (j == 2) sc[2] = -INFINITY;
            else sc[3] = -INFINITY;
        }
    }

    if (lane == 0) {
        const float denom = wsum + 1e-20f;
        #pragma unroll
        for (int k = 0; k < TOPK; ++k) {
            out_w[(size_t)token * TOPK + k] = wk[k] / denom;
            out_i[(size_t)token * TOPK + k] = (float)ik[k];
        }
    }
}

extern "C" void kernel_launch(void* const* d_in, const int* in_sizes, int n_in,
                              void* d_out, int out_size, void* d_ws, size_t ws_size,
                              hipStream_t stream) {
    const float* hidden = (const float*)d_in[0];
    const float* weight = (const float*)d_in[1];
    const float* bias   = (const float*)d_in[2];

    float* logits = (float*)d_out;                              // [T, E]
    float* out_w  = logits + (size_t)TKN * NE;                  // [T, 8]
    float* out_i  = out_w + (size_t)TKN * TOPK;                 // [T, 8]

    unsigned char* bpl = (unsigned char*)d_ws;                  // 4 MB B planes

    prep_b<<<512, 256, 0, stream>>>(weight, bpl);
    gemm_mfma<<<256, 1024, 0, stream>>>(hidden, bpl, logits);
    router_topk_kernel<<<TKN / 4, 256, 0, stream>>>(logits, bias, out_w, out_i);
}